// Round 4
// baseline (4520.091 us; speedup 1.0000x reference)
//
#include <hip/hip_runtime.h>
#include <math.h>

#define BTOT  65536
#define NN    6
#define EMBD  128
#define HIDD  256
#define PROJD 512
#define LAT2  128
#define TI    16
#define NTHR  1024
#define NEG   0.2f
#define MASKV (-1e9f)

// LDS: hbuf 96KB + stage 48KB = 144KB (<160KB) -> 1 block/CU, 16 waves.

template<int K, bool LAST>
__device__ __forceinline__ void gat_layer(
    float* hb, float* st,
    const float* __restrict__ W,
    const float* __restrict__ avec,
    int item, int lane, int tid,
    unsigned long long mz)
{
    const int c0 = lane << 2;           // 4 output cols per lane (covers 256)
    float wh[NN][4];
    #pragma unroll
    for (int i = 0; i < NN; ++i)
        #pragma unroll
        for (int c = 0; c < 4; ++c) wh[i][c] = 0.f;

    const float* hitem = hb + item * (NN * HIDD);   // [feat][node] layout

    // ---- Wh = h @ W, W staged in LDS 32-row chunks ----
    for (int k0 = 0; k0 < K; k0 += 32) {
        __syncthreads();
        {
            const int cc = (tid & 63) << 2;
            const int r0 = tid >> 6;           // 0..15
            *(float4*)(st + r0 * HIDD + cc) =
                *(const float4*)(W + (size_t)(k0 + r0) * HIDD + cc);
            *(float4*)(st + (r0 + 16) * HIDD + cc) =
                *(const float4*)(W + (size_t)(k0 + r0 + 16) * HIDD + cc);
        }
        __syncthreads();
        #pragma unroll
        for (int k = 0; k < 32; ++k) {
            const float* hr = hitem + (k0 + k) * NN;   // 6 contiguous floats
            float2 h01 = *(const float2*)(hr + 0);
            float2 h23 = *(const float2*)(hr + 2);
            float2 h45 = *(const float2*)(hr + 4);
            float av[NN] = {h01.x, h01.y, h23.x, h23.y, h45.x, h45.y};
            float4 bv = *(const float4*)(st + k * HIDD + c0);
            #pragma unroll
            for (int i = 0; i < NN; ++i) {
                wh[i][0] = fmaf(av[i], bv.x, wh[i][0]);
                wh[i][1] = fmaf(av[i], bv.y, wh[i][1]);
                wh[i][2] = fmaf(av[i], bv.z, wh[i][2]);
                wh[i][3] = fmaf(av[i], bv.w, wh[i][3]);
            }
        }
    }

    // ---- a_src/a_dst: partial dot + wave butterfly reduce ----
    float4 as4 = *(const float4*)(avec + c0);
    float4 ad4 = *(const float4*)(avec + HIDD + c0);
    float ps[NN], pd[NN];
    #pragma unroll
    for (int i = 0; i < NN; ++i) {
        ps[i] = wh[i][0]*as4.x + wh[i][1]*as4.y + wh[i][2]*as4.z + wh[i][3]*as4.w;
        pd[i] = wh[i][0]*ad4.x + wh[i][1]*ad4.y + wh[i][2]*ad4.z + wh[i][3]*ad4.w;
    }
    for (int off = 32; off > 0; off >>= 1) {
        #pragma unroll
        for (int i = 0; i < NN; ++i) {
            ps[i] += __shfl_xor(ps[i], off);
            pd[i] += __shfl_xor(pd[i], off);
        }
    }

    // ---- attention (lane-uniform, unnormalized-softmax aggregation) ----
    float rmax[NN];
    #pragma unroll
    for (int i = 0; i < NN; ++i) rmax[i] = -3.4e38f;
    #pragma unroll
    for (int i = 0; i < NN; ++i) {
        #pragma unroll
        for (int j = 0; j < NN; ++j) {
            float e = ps[i] + pd[j];
            e = (e > 0.f) ? e : NEG * e;
            if ((mz >> (i * 6 + j)) & 1ull) e = MASKV;
            rmax[i] = fmaxf(rmax[i], e);
        }
    }
    float rsum[NN] = {0.f, 0.f, 0.f, 0.f, 0.f, 0.f};
    float nh[NN][4];
    #pragma unroll
    for (int i = 0; i < NN; ++i)
        #pragma unroll
        for (int c = 0; c < 4; ++c) nh[i][c] = 0.f;

    #pragma unroll
    for (int j = 0; j < NN; ++j) {
        float s[NN];
        #pragma unroll
        for (int i = 0; i < NN; ++i) {
            float e = ps[i] + pd[j];
            e = (e > 0.f) ? e : NEG * e;
            if ((mz >> (i * 6 + j)) & 1ull) e = MASKV;
            s[i] = expf(e - rmax[i]);
            rsum[i] += s[i];
        }
        #pragma unroll
        for (int i = 0; i < NN; ++i) {
            nh[i][0] = fmaf(s[i], wh[j][0], nh[i][0]);
            nh[i][1] = fmaf(s[i], wh[j][1], nh[i][1]);
            nh[i][2] = fmaf(s[i], wh[j][2], nh[i][2]);
            nh[i][3] = fmaf(s[i], wh[j][3], nh[i][3]);
        }
    }

    // ---- normalize + relu + write back (wave-private region, no barrier) ----
    float* hout = hb + item * (NN * HIDD);
    #pragma unroll
    for (int i = 0; i < NN; ++i) {
        float rinv = 1.0f / rsum[i];
        if (LAST) {
            // transposed: [node][feat] == graph_repr layout
            float4 v;
            v.x = fmaxf(nh[i][0] * rinv, 0.f);
            v.y = fmaxf(nh[i][1] * rinv, 0.f);
            v.z = fmaxf(nh[i][2] * rinv, 0.f);
            v.w = fmaxf(nh[i][3] * rinv, 0.f);
            *(float4*)(hout + i * HIDD + c0) = v;
        } else {
            #pragma unroll
            for (int c = 0; c < 4; ++c)
                hout[(c0 + c) * NN + i] = fmaxf(nh[i][c] * rinv, 0.f);
        }
    }
}

__global__ __launch_bounds__(NTHR) void nge_fused(
    const int* __restrict__ numbers,
    const float* __restrict__ adj,
    const float* __restrict__ emb,
    const float* __restrict__ W0, const float* __restrict__ a0,
    const float* __restrict__ W1, const float* __restrict__ a1,
    const float* __restrict__ W2, const float* __restrict__ a2,
    const float* __restrict__ P1w, const float* __restrict__ P1b,
    const float* __restrict__ P2w, const float* __restrict__ P2b,
    float* __restrict__ out)
{
    __shared__ float hbuf[TI * NN * HIDD];   // 24576 floats = 96 KB
    __shared__ float stage[12288];           // 48 KB

    const int tid  = threadIdx.x;
    const int lane = tid & 63;
    const int item = tid >> 6;               // wave id == item id (GAT phases)
    const int bidx = blockIdx.x * TI + item;

    // ---- gather h0 = emb[numbers[b]] into [item][feat][node], feat<128 ----
    {
        int rows[NN];
        #pragma unroll
        for (int i = 0; i < NN; ++i) rows[i] = numbers[bidx * NN + i];
        float* hitem = hbuf + item * (NN * HIDD);
        #pragma unroll
        for (int i = 0; i < NN; ++i) {
            #pragma unroll
            for (int r = 0; r < 2; ++r) {
                int f = lane + (r << 6);
                hitem[f * NN + i] = emb[rows[i] * EMBD + f];
            }
        }
    }

    // ---- adj==0 mask, one bit per (i,j), built with one ballot ----
    unsigned long long mz;
    {
        float av = (lane < 36) ? adj[(size_t)bidx * 36 + lane] : 1.0f;
        mz = __ballot((lane < 36) && (av == 0.0f));
    }

    // ---- 3 GAT layers ----
    gat_layer<EMBD, false>(hbuf, stage, W0, a0, item, lane, tid, mz);
    gat_layer<HIDD, false>(hbuf, stage, W1, a1, item, lane, tid, mz);
    gat_layer<HIDD, true >(hbuf, stage, W2, a2, item, lane, tid, mz);

    // ---- P1: x = relu(gr @ P1w + P1b), gr = hbuf[item][node*256+feat] ----
    const int ct  = tid & 127;
    const int rt  = tid >> 7;        // 0..7 -> items {rt, rt+8}
    const int pc0 = ct << 2;         // 4 cols in [0,512)
    float acc[2][4];
    #pragma unroll
    for (int t = 0; t < 2; ++t)
        #pragma unroll
        for (int c = 0; c < 4; ++c) acc[t][c] = 0.f;

    for (int g0 = 0; g0 < NN * HIDD; g0 += 24) {
        __syncthreads();
        #pragma unroll
        for (int s = 0; s < 3; ++s) {
            int r = rt + 8 * s;
            *(float4*)(stage + r * PROJD + pc0) =
                *(const float4*)(P1w + (size_t)(g0 + r) * PROJD + pc0);
        }
        __syncthreads();
        #pragma unroll
        for (int r4 = 0; r4 < 24; r4 += 4) {
            float4 A0 = *(const float4*)(hbuf + rt * (NN * HIDD) + g0 + r4);
            float4 A1 = *(const float4*)(hbuf + (rt + 8) * (NN * HIDD) + g0 + r4);
            const float a0v[4] = {A0.x, A0.y, A0.z, A0.w};
            const float a1v[4] = {A1.x, A1.y, A1.z, A1.w};
            #pragma unroll
            for (int rr = 0; rr < 4; ++rr) {
                float4 bv = *(const float4*)(stage + (r4 + rr) * PROJD + pc0);
                acc[0][0] = fmaf(a0v[rr], bv.x, acc[0][0]);
                acc[0][1] = fmaf(a0v[rr], bv.y, acc[0][1]);
                acc[0][2] = fmaf(a0v[rr], bv.z, acc[0][2]);
                acc[0][3] = fmaf(a0v[rr], bv.w, acc[0][3]);
                acc[1][0] = fmaf(a1v[rr], bv.x, acc[1][0]);
                acc[1][1] = fmaf(a1v[rr], bv.y, acc[1][1]);
                acc[1][2] = fmaf(a1v[rr], bv.z, acc[1][2]);
                acc[1][3] = fmaf(a1v[rr], bv.w, acc[1][3]);
            }
        }
    }
    __syncthreads();   // all gr reads done before overwriting hbuf with x
    {
        float4 b1 = *(const float4*)(P1b + pc0);
        #pragma unroll
        for (int t = 0; t < 2; ++t) {
            int it = rt + 8 * t;
            float4 xv;
            xv.x = fmaxf(acc[t][0] + b1.x, 0.f);
            xv.y = fmaxf(acc[t][1] + b1.y, 0.f);
            xv.z = fmaxf(acc[t][2] + b1.z, 0.f);
            xv.w = fmaxf(acc[t][3] + b1.w, 0.f);
            *(float4*)(hbuf + it * PROJD + pc0) = xv;   // x[item][512]
        }
    }

    // ---- P2: latent = x @ P2w + P2b; split mu/logvar ----
    const int j0 = lane << 1;        // 2 cols in [0,128)
    float acc2x = 0.f, acc2y = 0.f;
    for (int g0 = 0; g0 < PROJD; g0 += 64) {
        __syncthreads();
        {
            int r  = tid >> 5;           // 0..31
            int cc = (tid & 31) << 2;    // 0..124
            *(float4*)(stage + r * LAT2 + cc) =
                *(const float4*)(P2w + (size_t)(g0 + r) * LAT2 + cc);
            *(float4*)(stage + (r + 32) * LAT2 + cc) =
                *(const float4*)(P2w + (size_t)(g0 + r + 32) * LAT2 + cc);
        }
        __syncthreads();
        const float* xit = hbuf + item * PROJD + g0;
        #pragma unroll
        for (int r4 = 0; r4 < 64; r4 += 4) {
            float4 A = *(const float4*)(xit + r4);
            const float av[4] = {A.x, A.y, A.z, A.w};
            #pragma unroll
            for (int rr = 0; rr < 4; ++rr) {
                float2 bv = *(const float2*)(stage + (r4 + rr) * LAT2 + j0);
                acc2x = fmaf(av[rr], bv.x, acc2x);
                acc2y = fmaf(av[rr], bv.y, acc2y);
            }
        }
    }
    {
        float o0 = acc2x + P2b[j0];
        float o1 = acc2y + P2b[j0 + 1];
        size_t base = (size_t)bidx * 64;
        float2 v; v.x = o0; v.y = o1;
        if (j0 < 64) {
            *(float2*)(out + base + j0) = v;                           // mu
        } else {
            *(float2*)(out + (size_t)BTOT * 64 + base + (j0 - 64)) = v; // logvar
        }
    }
}

extern "C" void kernel_launch(void* const* d_in, const int* in_sizes, int n_in,
                              void* d_out, int out_size, void* d_ws, size_t ws_size,
                              hipStream_t stream) {
    const int*   numbers = (const int*)  d_in[0];
    const float* adj     = (const float*)d_in[1];
    const float* emb     = (const float*)d_in[2];
    const float* W0      = (const float*)d_in[3];
    const float* a0      = (const float*)d_in[4];
    const float* W1      = (const float*)d_in[5];
    const float* a1      = (const float*)d_in[6];
    const float* W2      = (const float*)d_in[7];
    const float* a2      = (const float*)d_in[8];
    const float* P1w     = (const float*)d_in[9];
    const float* P1b     = (const float*)d_in[10];
    const float* P2w     = (const float*)d_in[11];
    const float* P2b     = (const float*)d_in[12];
    float* out = (float*)d_out;

    dim3 grid(BTOT / TI);   // 4096 blocks, 16 items each
    nge_fused<<<grid, NTHR, 0, stream>>>(numbers, adj, emb,
                                         W0, a0, W1, a1, W2, a2,
                                         P1w, P1b, P2w, P2b, out);
}

// Round 5
// 4512.682 us; speedup vs baseline: 1.0016x; 1.0016x over previous
//
#include <hip/hip_runtime.h>
#include <math.h>

#define BTOT  65536
#define NN    6
#define EMBD  128
#define HIDD  256
#define PROJD 512
#define LAT2  128
#define TI    16
#define NTHR  1024
#define NEG   0.2f
#define MASKV (-1e9f)

// LDS: hbuf 96KB + stage 48KB = 144KB (<160KB) -> 1 block/CU, 16 waves.

template<int K, bool LAST>
__device__ __forceinline__ void gat_layer(
    float* hb, float* st,
    const float* __restrict__ W,
    const float* __restrict__ avec,
    int item, int lane, int tid,
    unsigned long long mz)
{
    const int c0 = lane << 2;           // 4 output cols per lane (covers 256)
    float wh[NN][4];
    #pragma unroll
    for (int i = 0; i < NN; ++i)
        #pragma unroll
        for (int c = 0; c < 4; ++c) wh[i][c] = 0.f;

    const float* hitem = hb + item * (NN * HIDD);   // [feat][node] layout

    // ---- Wh = h @ W, W staged in LDS 32-row chunks ----
    for (int k0 = 0; k0 < K; k0 += 32) {
        __syncthreads();
        {
            const int cc = (tid & 63) << 2;
            const int r0 = tid >> 6;           // 0..15
            *(float4*)(st + r0 * HIDD + cc) =
                *(const float4*)(W + (size_t)(k0 + r0) * HIDD + cc);
            *(float4*)(st + (r0 + 16) * HIDD + cc) =
                *(const float4*)(W + (size_t)(k0 + r0 + 16) * HIDD + cc);
        }
        __syncthreads();
        #pragma unroll
        for (int k = 0; k < 32; ++k) {
            const float* hr = hitem + (k0 + k) * NN;   // 6 contiguous floats
            float2 h01 = *(const float2*)(hr + 0);
            float2 h23 = *(const float2*)(hr + 2);
            float2 h45 = *(const float2*)(hr + 4);
            float av[NN] = {h01.x, h01.y, h23.x, h23.y, h45.x, h45.y};
            float4 bv = *(const float4*)(st + k * HIDD + c0);
            #pragma unroll
            for (int i = 0; i < NN; ++i) {
                wh[i][0] = fmaf(av[i], bv.x, wh[i][0]);
                wh[i][1] = fmaf(av[i], bv.y, wh[i][1]);
                wh[i][2] = fmaf(av[i], bv.z, wh[i][2]);
                wh[i][3] = fmaf(av[i], bv.w, wh[i][3]);
            }
        }
    }

    // ---- a_src/a_dst: partial dot + wave butterfly reduce ----
    float4 as4 = *(const float4*)(avec + c0);
    float4 ad4 = *(const float4*)(avec + HIDD + c0);
    float ps[NN], pd[NN];
    #pragma unroll
    for (int i = 0; i < NN; ++i) {
        ps[i] = wh[i][0]*as4.x + wh[i][1]*as4.y + wh[i][2]*as4.z + wh[i][3]*as4.w;
        pd[i] = wh[i][0]*ad4.x + wh[i][1]*ad4.y + wh[i][2]*ad4.z + wh[i][3]*ad4.w;
    }
    for (int off = 32; off > 0; off >>= 1) {
        #pragma unroll
        for (int i = 0; i < NN; ++i) {
            ps[i] += __shfl_xor(ps[i], off);
            pd[i] += __shfl_xor(pd[i], off);
        }
    }

    // ---- attention (lane-uniform, unnormalized-softmax aggregation) ----
    float rmax[NN];
    #pragma unroll
    for (int i = 0; i < NN; ++i) rmax[i] = -3.4e38f;
    #pragma unroll
    for (int i = 0; i < NN; ++i) {
        #pragma unroll
        for (int j = 0; j < NN; ++j) {
            float e = ps[i] + pd[j];
            e = (e > 0.f) ? e : NEG * e;
            if ((mz >> (i * 6 + j)) & 1ull) e = MASKV;
            rmax[i] = fmaxf(rmax[i], e);
        }
    }
    float rsum[NN] = {0.f, 0.f, 0.f, 0.f, 0.f, 0.f};
    float nh[NN][4];
    #pragma unroll
    for (int i = 0; i < NN; ++i)
        #pragma unroll
        for (int c = 0; c < 4; ++c) nh[i][c] = 0.f;

    #pragma unroll
    for (int j = 0; j < NN; ++j) {
        float s[NN];
        #pragma unroll
        for (int i = 0; i < NN; ++i) {
            float e = ps[i] + pd[j];
            e = (e > 0.f) ? e : NEG * e;
            if ((mz >> (i * 6 + j)) & 1ull) e = MASKV;
            s[i] = expf(e - rmax[i]);
            rsum[i] += s[i];
        }
        #pragma unroll
        for (int i = 0; i < NN; ++i) {
            nh[i][0] = fmaf(s[i], wh[j][0], nh[i][0]);
            nh[i][1] = fmaf(s[i], wh[j][1], nh[i][1]);
            nh[i][2] = fmaf(s[i], wh[j][2], nh[i][2]);
            nh[i][3] = fmaf(s[i], wh[j][3], nh[i][3]);
        }
    }

    // ---- normalize + relu + write back (wave-private region, no barrier) ----
    float* hout = hb + item * (NN * HIDD);
    #pragma unroll
    for (int i = 0; i < NN; ++i) {
        float rinv = 1.0f / rsum[i];
        if (LAST) {
            // transposed: [node][feat] == graph_repr layout
            float4 v;
            v.x = fmaxf(nh[i][0] * rinv, 0.f);
            v.y = fmaxf(nh[i][1] * rinv, 0.f);
            v.z = fmaxf(nh[i][2] * rinv, 0.f);
            v.w = fmaxf(nh[i][3] * rinv, 0.f);
            *(float4*)(hout + i * HIDD + c0) = v;
        } else {
            #pragma unroll
            for (int c = 0; c < 4; ++c)
                hout[(c0 + c) * NN + i] = fmaxf(nh[i][c] * rinv, 0.f);
        }
    }
}

__global__ __launch_bounds__(NTHR) void nge_fused(
    const int* __restrict__ numbers,
    const float* __restrict__ adj,
    const float* __restrict__ emb,
    const float* __restrict__ W0, const float* __restrict__ a0,
    const float* __restrict__ W1, const float* __restrict__ a1,
    const float* __restrict__ W2, const float* __restrict__ a2,
    const float* __restrict__ P1w, const float* __restrict__ P1b,
    const float* __restrict__ P2w, const float* __restrict__ P2b,
    float* __restrict__ out)
{
    __shared__ float hbuf[TI * NN * HIDD];   // 24576 floats = 96 KB
    __shared__ float stage[12288];           // 48 KB

    const int tid  = threadIdx.x;
    const int lane = tid & 63;
    const int item = tid >> 6;               // wave id == item id (GAT phases)
    const int bidx = blockIdx.x * TI + item;

    // ---- gather h0 = emb[numbers[b]] into [item][feat][node], feat<128 ----
    {
        int rows[NN];
        #pragma unroll
        for (int i = 0; i < NN; ++i) rows[i] = numbers[bidx * NN + i];
        float* hitem = hbuf + item * (NN * HIDD);
        #pragma unroll
        for (int i = 0; i < NN; ++i) {
            #pragma unroll
            for (int r = 0; r < 2; ++r) {
                int f = lane + (r << 6);
                hitem[f * NN + i] = emb[rows[i] * EMBD + f];
            }
        }
    }

    // ---- adj==0 mask, one bit per (i,j), built with one ballot ----
    unsigned long long mz;
    {
        float av = (lane < 36) ? adj[(size_t)bidx * 36 + lane] : 1.0f;
        mz = __ballot((lane < 36) && (av == 0.0f));
    }

    // ---- 3 GAT layers ----
    gat_layer<EMBD, false>(hbuf, stage, W0, a0, item, lane, tid, mz);
    gat_layer<HIDD, false>(hbuf, stage, W1, a1, item, lane, tid, mz);
    gat_layer<HIDD, true >(hbuf, stage, W2, a2, item, lane, tid, mz);

    // ---- P1: x = relu(gr @ P1w + P1b), gr = hbuf[item][node*256+feat] ----
    const int ct  = tid & 127;
    const int rt  = tid >> 7;        // 0..7 -> items {rt, rt+8}
    const int pc0 = ct << 2;         // 4 cols in [0,512)
    float acc[2][4];
    #pragma unroll
    for (int t = 0; t < 2; ++t)
        #pragma unroll
        for (int c = 0; c < 4; ++c) acc[t][c] = 0.f;

    for (int g0 = 0; g0 < NN * HIDD; g0 += 24) {
        __syncthreads();
        #pragma unroll
        for (int s = 0; s < 3; ++s) {
            int r = rt + 8 * s;
            *(float4*)(stage + r * PROJD + pc0) =
                *(const float4*)(P1w + (size_t)(g0 + r) * PROJD + pc0);
        }
        __syncthreads();
        #pragma unroll
        for (int r4 = 0; r4 < 24; r4 += 4) {
            float4 A0 = *(const float4*)(hbuf + rt * (NN * HIDD) + g0 + r4);
            float4 A1 = *(const float4*)(hbuf + (rt + 8) * (NN * HIDD) + g0 + r4);
            const float a0v[4] = {A0.x, A0.y, A0.z, A0.w};
            const float a1v[4] = {A1.x, A1.y, A1.z, A1.w};
            #pragma unroll
            for (int rr = 0; rr < 4; ++rr) {
                float4 bv = *(const float4*)(stage + (r4 + rr) * PROJD + pc0);
                acc[0][0] = fmaf(a0v[rr], bv.x, acc[0][0]);
                acc[0][1] = fmaf(a0v[rr], bv.y, acc[0][1]);
                acc[0][2] = fmaf(a0v[rr], bv.z, acc[0][2]);
                acc[0][3] = fmaf(a0v[rr], bv.w, acc[0][3]);
                acc[1][0] = fmaf(a1v[rr], bv.x, acc[1][0]);
                acc[1][1] = fmaf(a1v[rr], bv.y, acc[1][1]);
                acc[1][2] = fmaf(a1v[rr], bv.z, acc[1][2]);
                acc[1][3] = fmaf(a1v[rr], bv.w, acc[1][3]);
            }
        }
    }
    __syncthreads();   // all gr reads done before overwriting hbuf with x
    {
        float4 b1 = *(const float4*)(P1b + pc0);
        #pragma unroll
        for (int t = 0; t < 2; ++t) {
            int it = rt + 8 * t;
            float4 xv;
            xv.x = fmaxf(acc[t][0] + b1.x, 0.f);
            xv.y = fmaxf(acc[t][1] + b1.y, 0.f);
            xv.z = fmaxf(acc[t][2] + b1.z, 0.f);
            xv.w = fmaxf(acc[t][3] + b1.w, 0.f);
            *(float4*)(hbuf + it * PROJD + pc0) = xv;   // x[item][512]
        }
    }

    // ---- P2: latent = x @ P2w + P2b; split mu/logvar ----
    const int j0 = lane << 1;        // 2 cols in [0,128)
    float acc2x = 0.f, acc2y = 0.f;
    for (int g0 = 0; g0 < PROJD; g0 += 64) {
        __syncthreads();
        {
            int r  = tid >> 5;           // 0..31
            int cc = (tid & 31) << 2;    // 0..124
            *(float4*)(stage + r * LAT2 + cc) =
                *(const float4*)(P2w + (size_t)(g0 + r) * LAT2 + cc);
            *(float4*)(stage + (r + 32) * LAT2 + cc) =
                *(const float4*)(P2w + (size_t)(g0 + r + 32) * LAT2 + cc);
        }
        __syncthreads();
        const float* xit = hbuf + item * PROJD + g0;
        #pragma unroll
        for (int r4 = 0; r4 < 64; r4 += 4) {
            float4 A = *(const float4*)(xit + r4);
            const float av[4] = {A.x, A.y, A.z, A.w};
            #pragma unroll
            for (int rr = 0; rr < 4; ++rr) {
                float2 bv = *(const float2*)(stage + (r4 + rr) * LAT2 + j0);
                acc2x = fmaf(av[rr], bv.x, acc2x);
                acc2y = fmaf(av[rr], bv.y, acc2y);
            }
        }
    }
    {
        float o0 = acc2x + P2b[j0];
        float o1 = acc2y + P2b[j0 + 1];
        size_t base = (size_t)bidx * 64;
        float2 v; v.x = o0; v.y = o1;
        if (j0 < 64) {
            *(float2*)(out + base + j0) = v;                           // mu
        } else {
            *(float2*)(out + (size_t)BTOT * 64 + base + (j0 - 64)) = v; // logvar
        }
    }
}

extern "C" void kernel_launch(void* const* d_in, const int* in_sizes, int n_in,
                              void* d_out, int out_size, void* d_ws, size_t ws_size,
                              hipStream_t stream) {
    const int*   numbers = (const int*)  d_in[0];
    const float* adj     = (const float*)d_in[1];
    const float* emb     = (const float*)d_in[2];
    const float* W0      = (const float*)d_in[3];
    const float* a0      = (const float*)d_in[4];
    const float* W1      = (const float*)d_in[5];
    const float* a1      = (const float*)d_in[6];
    const float* W2      = (const float*)d_in[7];
    const float* a2      = (const float*)d_in[8];
    const float* P1w     = (const float*)d_in[9];
    const float* P1b     = (const float*)d_in[10];
    const float* P2w     = (const float*)d_in[11];
    const float* P2b     = (const float*)d_in[12];
    float* out = (float*)d_out;

    dim3 grid(BTOT / TI);   // 4096 blocks, 16 items each
    nge_fused<<<grid, NTHR, 0, stream>>>(numbers, adj, emb,
                                         W0, a0, W1, a1, W2, a2,
                                         P1w, P1b, P2w, P2b, out);
}

// Round 6
// 1648.083 us; speedup vs baseline: 2.7426x; 2.7381x over previous
//
#include <hip/hip_runtime.h>
#include <math.h>

#define BTOT  65536
#define NN    6
#define NEG   0.2f
#define MASKV (-1e9f)

typedef short bf16x8 __attribute__((ext_vector_type(8)));
typedef float f32x4  __attribute__((ext_vector_type(4)));

// ws layout: fragment-linear hi/lo bf16 weights, 1024B per frag, [nt][kk][hi/lo]
#define OFF_W0 0u
#define OFF_W1 131072u
#define OFF_W2 393216u
#define OFF_P1 655360u
#define OFF_P2 3801088u
#define WS_NEED 4063232ull

__device__ __forceinline__ f32x4 mfma16(bf16x8 a, bf16x8 b, f32x4 c){
  return __builtin_amdgcn_mfma_f32_16x16x32_bf16(a, b, c, 0, 0, 0);
}

// truncation split: x = hi + lo, hi = top16(x), lo = top16(x - hi); residual ~2^-15 rel
__device__ __forceinline__ void split8(float4 x0, float4 x1, bf16x8& h, bf16x8& l){
  float xs[8] = {x0.x,x0.y,x0.z,x0.w,x1.x,x1.y,x1.z,x1.w};
  #pragma unroll
  for (int e=0;e<8;++e){
    unsigned u = __float_as_uint(xs[e]);
    float hf = __uint_as_float(u & 0xFFFF0000u);
    h[e] = (short)(u >> 16);
    l[e] = (short)(__float_as_uint(xs[e] - hf) >> 16);
  }
}

// XOR-swizzled LDS addressing (strides == 8 mod 32; swizzle restores uniform banks)
__device__ __forceinline__ int hword(int r, int c){ return r*264  + (c ^ ((r&7)<<2)); }
__device__ __forceinline__ int gword(int r, int c){ return r*1544 + (c ^ ((r&7)<<2)); }
__device__ __forceinline__ int xword(int r, int c){ return r*520  + (c ^ ((r&7)<<2)); }

// ---------------- pre-kernel: fp32 weights -> frag-linear hi/lo bf16 in ws -------------
__global__ __launch_bounds__(64) void fragize(
    const float* __restrict__ W0, const float* __restrict__ W1,
    const float* __restrict__ W2, const float* __restrict__ P1w,
    const float* __restrict__ P2w, char* __restrict__ ws)
{
  int fid = blockIdx.x;           // 0..1983
  int lane = threadIdx.x;         // 0..63
  const float* src; int KK, N; unsigned off; int idx;
  if (fid < 64)        { src = W0;  KK = 4;  N = 256; off = OFF_W0; idx = fid; }
  else if (fid < 192)  { src = W1;  KK = 8;  N = 256; off = OFF_W1; idx = fid - 64; }
  else if (fid < 320)  { src = W2;  KK = 8;  N = 256; off = OFF_W2; idx = fid - 192; }
  else if (fid < 1856) { src = P1w; KK = 48; N = 512; off = OFF_P1; idx = fid - 320; }
  else                 { src = P2w; KK = 16; N = 128; off = OFF_P2; idx = fid - 1856; }
  int nt = idx / KK, kk = idx % KK;
  int n  = nt*16 + (lane & 15);
  int kb = kk*32 + (lane >> 4)*8;
  bf16x8 h, l;
  #pragma unroll
  for (int e=0;e<8;++e){
    float x = src[(size_t)(kb+e)*N + n];
    unsigned u = __float_as_uint(x);
    float hf = __uint_as_float(u & 0xFFFF0000u);
    h[e] = (short)(u >> 16);
    l[e] = (short)(__float_as_uint(x - hf) >> 16);
  }
  char* dst = ws + off + (size_t)idx*2048 + (size_t)lane*16;
  *(bf16x8*)dst = h;
  *(bf16x8*)(dst + 1024) = l;
}

// ---------------- fp32 attention epilogue (wave = item) --------------------------------
template<bool LAST>
__device__ __forceinline__ void attention_phase(float* hb, const float* __restrict__ avec,
    int w, int lane, unsigned long long mz)
{
  const int c0 = lane << 2;
  float wh[NN][4];
  #pragma unroll
  for (int i=0;i<NN;++i){
    float4 t = *(const float4*)(hb + hword(w*NN+i, c0));
    wh[i][0]=t.x; wh[i][1]=t.y; wh[i][2]=t.z; wh[i][3]=t.w;
  }
  float4 as4 = *(const float4*)(avec + c0);
  float4 ad4 = *(const float4*)(avec + 256 + c0);
  float ps[NN], pd[NN];
  #pragma unroll
  for (int i=0;i<NN;++i){
    ps[i] = wh[i][0]*as4.x + wh[i][1]*as4.y + wh[i][2]*as4.z + wh[i][3]*as4.w;
    pd[i] = wh[i][0]*ad4.x + wh[i][1]*ad4.y + wh[i][2]*ad4.z + wh[i][3]*ad4.w;
  }
  for (int off=32; off>0; off>>=1){
    #pragma unroll
    for (int i=0;i<NN;++i){ ps[i]+=__shfl_xor(ps[i],off); pd[i]+=__shfl_xor(pd[i],off); }
  }
  float rmax[NN];
  #pragma unroll
  for (int i=0;i<NN;++i) rmax[i] = -3.4e38f;
  #pragma unroll
  for (int i=0;i<NN;++i){
    #pragma unroll
    for (int j=0;j<NN;++j){
      float e = ps[i] + pd[j];
      e = (e > 0.f) ? e : NEG*e;
      if ((mz >> (i*6+j)) & 1ull) e = MASKV;
      rmax[i] = fmaxf(rmax[i], e);
    }
  }
  float rsum[NN] = {0.f,0.f,0.f,0.f,0.f,0.f};
  float nh[NN][4];
  #pragma unroll
  for (int i=0;i<NN;++i){ nh[i][0]=0.f; nh[i][1]=0.f; nh[i][2]=0.f; nh[i][3]=0.f; }
  #pragma unroll
  for (int j=0;j<NN;++j){
    float s[NN];
    #pragma unroll
    for (int i=0;i<NN;++i){
      float e = ps[i] + pd[j];
      e = (e > 0.f) ? e : NEG*e;
      if ((mz >> (i*6+j)) & 1ull) e = MASKV;
      s[i] = expf(e - rmax[i]);
      rsum[i] += s[i];
    }
    #pragma unroll
    for (int i=0;i<NN;++i){
      nh[i][0] = fmaf(s[i], wh[j][0], nh[i][0]);
      nh[i][1] = fmaf(s[i], wh[j][1], nh[i][1]);
      nh[i][2] = fmaf(s[i], wh[j][2], nh[i][2]);
      nh[i][3] = fmaf(s[i], wh[j][3], nh[i][3]);
    }
  }
  if (LAST) __syncthreads();   // gr rows overlap other items' Wh rows
  #pragma unroll
  for (int i=0;i<NN;++i){
    float rinv = 1.0f / rsum[i];
    float4 v;
    v.x = fmaxf(nh[i][0]*rinv, 0.f);
    v.y = fmaxf(nh[i][1]*rinv, 0.f);
    v.z = fmaxf(nh[i][2]*rinv, 0.f);
    v.w = fmaxf(nh[i][3]*rinv, 0.f);
    if (LAST) *(float4*)(hb + gword(w, i*256 + c0)) = v;
    else      *(float4*)(hb + hword(w*NN+i, c0)) = v;
  }
}

// ---------------- one GAT layer: MFMA GEMM (96xKx256) + attention ----------------------
template<int KK, bool LAST>
__device__ __forceinline__ void gat_layer_mfma(float* hb, const char* __restrict__ wf,
    const float* __restrict__ avec, int w, int lane, unsigned long long mz)
{
  const int mh = w >> 3, nq = w & 7;
  const int arow = lane & 15, kgrp = lane >> 4;
  f32x4 z = {0.f,0.f,0.f,0.f};
  f32x4 acc[3][2];
  #pragma unroll
  for (int mt=0;mt<3;++mt){ acc[mt][0]=z; acc[mt][1]=z; }
  const char* wb0 = wf + (size_t)(2*nq)*KK*2048 + (size_t)lane*16;
  const char* wb1 = wb0 + (size_t)KK*2048;
  bf16x8 b0h = *(const bf16x8*)(wb0);
  bf16x8 b0l = *(const bf16x8*)(wb0 + 1024);
  bf16x8 b1h = *(const bf16x8*)(wb1);
  bf16x8 b1l = *(const bf16x8*)(wb1 + 1024);
  for (int kk=0; kk<KK; ++kk){
    int kn = (kk+1 < KK) ? kk+1 : kk;
    bf16x8 n0h = *(const bf16x8*)(wb0 + kn*2048);
    bf16x8 n0l = *(const bf16x8*)(wb0 + kn*2048 + 1024);
    bf16x8 n1h = *(const bf16x8*)(wb1 + kn*2048);
    bf16x8 n1l = *(const bf16x8*)(wb1 + kn*2048 + 1024);
    #pragma unroll
    for (int mt=0; mt<3; ++mt){
      int row = (mh*3+mt)*16 + arow;
      int c   = kk*32 + kgrp*8;
      float4 x0 = *(const float4*)(hb + hword(row, c));
      float4 x1 = *(const float4*)(hb + hword(row, c+4));
      bf16x8 ah, al; split8(x0, x1, ah, al);
      acc[mt][0] = mfma16(ah, b0h, acc[mt][0]);
      acc[mt][0] = mfma16(al, b0h, acc[mt][0]);
      acc[mt][0] = mfma16(ah, b0l, acc[mt][0]);
      acc[mt][1] = mfma16(ah, b1h, acc[mt][1]);
      acc[mt][1] = mfma16(al, b1h, acc[mt][1]);
      acc[mt][1] = mfma16(ah, b1l, acc[mt][1]);
    }
    b0h=n0h; b0l=n0l; b1h=n1h; b1l=n1l;
  }
  __syncthreads();          // all h reads done before Wh overwrite
  #pragma unroll
  for (int mt=0;mt<3;++mt)
    #pragma unroll
    for (int nt=0;nt<2;++nt)
      #pragma unroll
      for (int v=0;v<4;++v)
        hb[hword((mh*3+mt)*16 + kgrp*4 + v, (nq*2+nt)*16 + arow)] = acc[mt][nt][v];
  __syncthreads();
  attention_phase<LAST>(hb, avec, w, lane, mz);
  __syncthreads();
}

// ---------------- main fused kernel -----------------------------------------------------
__global__ __launch_bounds__(1024) void nge_mfma(
    const int* __restrict__ numbers, const float* __restrict__ adj,
    const float* __restrict__ emb,
    const float* __restrict__ a0, const float* __restrict__ a1,
    const float* __restrict__ a2,
    const float* __restrict__ P1b, const float* __restrict__ P2b,
    const char* __restrict__ wfrag, float* __restrict__ out)
{
  __shared__ float hb[96*264];   // 101,376 B

  const int tid  = threadIdx.x;
  const int lane = tid & 63;
  const int w    = tid >> 6;                 // wave id (0..15)
  const int itemg = blockIdx.x*16 + w;

  // gather h0 = emb[numbers] into [row=item*6+node][feat]
  {
    int rows[NN];
    #pragma unroll
    for (int i=0;i<NN;++i) rows[i] = numbers[itemg*NN + i];
    #pragma unroll
    for (int i=0;i<NN;++i){
      #pragma unroll
      for (int r=0;r<2;++r){
        int f = lane + (r<<6);
        hb[hword(w*NN+i, f)] = emb[rows[i]*128 + f];
      }
    }
  }
  unsigned long long mz;
  {
    float av = (lane < 36) ? adj[(size_t)itemg*36 + lane] : 1.0f;
    mz = __ballot((lane < 36) && (av == 0.0f));
  }
  __syncthreads();

  gat_layer_mfma<4, false>(hb, wfrag + OFF_W0, a0, w, lane, mz);
  gat_layer_mfma<8, false>(hb, wfrag + OFF_W1, a1, w, lane, mz);
  gat_layer_mfma<8, true >(hb, wfrag + OFF_W2, a2, w, lane, mz);

  const int arow = lane & 15, kgrp = lane >> 4;

  // ---- P1: x[16][512] = relu(gr[16][1536] @ P1w + P1b), wave owns 2 N-tiles ----
  {
    f32x4 z = {0.f,0.f,0.f,0.f};
    f32x4 pa0 = z, pa1 = z;
    const char* pb0 = wfrag + OFF_P1 + (size_t)(2*w)*48*2048 + (size_t)lane*16;
    const char* pb1 = pb0 + (size_t)48*2048;
    bf16x8 b0h = *(const bf16x8*)(pb0);
    bf16x8 b0l = *(const bf16x8*)(pb0 + 1024);
    bf16x8 b1h = *(const bf16x8*)(pb1);
    bf16x8 b1l = *(const bf16x8*)(pb1 + 1024);
    for (int kk=0; kk<48; ++kk){
      int kn = (kk < 47) ? kk+1 : kk;
      bf16x8 n0h = *(const bf16x8*)(pb0 + kn*2048);
      bf16x8 n0l = *(const bf16x8*)(pb0 + kn*2048 + 1024);
      bf16x8 n1h = *(const bf16x8*)(pb1 + kn*2048);
      bf16x8 n1l = *(const bf16x8*)(pb1 + kn*2048 + 1024);
      int c = kk*32 + kgrp*8;
      float4 x0 = *(const float4*)(hb + gword(arow, c));
      float4 x1 = *(const float4*)(hb + gword(arow, c+4));
      bf16x8 ah, al; split8(x0, x1, ah, al);
      pa0 = mfma16(ah, b0h, pa0);
      pa0 = mfma16(al, b0h, pa0);
      pa0 = mfma16(ah, b0l, pa0);
      pa1 = mfma16(ah, b1h, pa1);
      pa1 = mfma16(al, b1h, pa1);
      pa1 = mfma16(ah, b1l, pa1);
      b0h=n0h; b0l=n0l; b1h=n1h; b1l=n1l;
    }
    __syncthreads();   // gr reads done before x overwrite
    #pragma unroll
    for (int nt=0;nt<2;++nt){
      int col = (2*w+nt)*16 + arow;
      float bv = P1b[col];
      f32x4 pa = nt ? pa1 : pa0;
      #pragma unroll
      for (int v=0;v<4;++v){
        int it = kgrp*4 + v;
        hb[xword(it, col)] = fmaxf(pa[v] + bv, 0.f);
      }
    }
    __syncthreads();
  }

  // ---- P2: latent[16][128] = x @ P2w + P2b (waves 0..7) ----
  if (w < 8){
    f32x4 pc = {0.f,0.f,0.f,0.f};
    const char* qb = wfrag + OFF_P2 + (size_t)w*16*2048 + (size_t)lane*16;
    bf16x8 bh = *(const bf16x8*)(qb);
    bf16x8 bl = *(const bf16x8*)(qb + 1024);
    for (int kk=0; kk<16; ++kk){
      int kn = (kk < 15) ? kk+1 : kk;
      bf16x8 nh2 = *(const bf16x8*)(qb + kn*2048);
      bf16x8 nl2 = *(const bf16x8*)(qb + kn*2048 + 1024);
      int c = kk*32 + kgrp*8;
      float4 x0 = *(const float4*)(hb + xword(arow, c));
      float4 x1 = *(const float4*)(hb + xword(arow, c+4));
      bf16x8 ah, al; split8(x0, x1, ah, al);
      pc = mfma16(ah, bh, pc);
      pc = mfma16(al, bh, pc);
      pc = mfma16(ah, bl, pc);
      bh = nh2; bl = nl2;
    }
    int col = w*16 + arow;
    float bv = P2b[col];
    #pragma unroll
    for (int v=0;v<4;++v){
      int itl = kgrp*4 + v;
      size_t ig = (size_t)blockIdx.x*16 + itl;
      float val = pc[v] + bv;
      if (col < 64) out[ig*64 + col] = val;
      else          out[(size_t)BTOT*64 + ig*64 + (col - 64)] = val;
    }
  }
}

// ======================= fallback fp32 kernel (ws too small) ===========================
#define EMBD  128
#define HIDD  256
#define PROJD 512
#define LAT2  128
#define TI    16
#define NTHR  1024

template<int K, bool LAST>
__device__ __forceinline__ void gat_layer(
    float* hb, float* st,
    const float* __restrict__ W,
    const float* __restrict__ avec,
    int item, int lane, int tid,
    unsigned long long mz)
{
    const int c0 = lane << 2;
    float wh[NN][4];
    #pragma unroll
    for (int i = 0; i < NN; ++i)
        #pragma unroll
        for (int c = 0; c < 4; ++c) wh[i][c] = 0.f;
    const float* hitem = hb + item * (NN * HIDD);
    for (int k0 = 0; k0 < K; k0 += 32) {
        __syncthreads();
        {
            const int cc = (tid & 63) << 2;
            const int r0 = tid >> 6;
            *(float4*)(st + r0 * HIDD + cc) =
                *(const float4*)(W + (size_t)(k0 + r0) * HIDD + cc);
            *(float4*)(st + (r0 + 16) * HIDD + cc) =
                *(const float4*)(W + (size_t)(k0 + r0 + 16) * HIDD + cc);
        }
        __syncthreads();
        #pragma unroll
        for (int k = 0; k < 32; ++k) {
            const float* hr = hitem + (k0 + k) * NN;
            float2 h01 = *(const float2*)(hr + 0);
            float2 h23 = *(const float2*)(hr + 2);
            float2 h45 = *(const float2*)(hr + 4);
            float av[NN] = {h01.x, h01.y, h23.x, h23.y, h45.x, h45.y};
            float4 bv = *(const float4*)(st + k * HIDD + c0);
            #pragma unroll
            for (int i = 0; i < NN; ++i) {
                wh[i][0] = fmaf(av[i], bv.x, wh[i][0]);
                wh[i][1] = fmaf(av[i], bv.y, wh[i][1]);
                wh[i][2] = fmaf(av[i], bv.z, wh[i][2]);
                wh[i][3] = fmaf(av[i], bv.w, wh[i][3]);
            }
        }
    }
    float4 as4 = *(const float4*)(avec + c0);
    float4 ad4 = *(const float4*)(avec + HIDD + c0);
    float ps[NN], pd[NN];
    #pragma unroll
    for (int i = 0; i < NN; ++i) {
        ps[i] = wh[i][0]*as4.x + wh[i][1]*as4.y + wh[i][2]*as4.z + wh[i][3]*as4.w;
        pd[i] = wh[i][0]*ad4.x + wh[i][1]*ad4.y + wh[i][2]*ad4.z + wh[i][3]*ad4.w;
    }
    for (int off = 32; off > 0; off >>= 1) {
        #pragma unroll
        for (int i = 0; i < NN; ++i) {
            ps[i] += __shfl_xor(ps[i], off);
            pd[i] += __shfl_xor(pd[i], off);
        }
    }
    float rmax[NN];
    #pragma unroll
    for (int i = 0; i < NN; ++i) rmax[i] = -3.4e38f;
    #pragma unroll
    for (int i = 0; i < NN; ++i) {
        #pragma unroll
        for (int j = 0; j < NN; ++j) {
            float e = ps[i] + pd[j];
            e = (e > 0.f) ? e : NEG * e;
            if ((mz >> (i * 6 + j)) & 1ull) e = MASKV;
            rmax[i] = fmaxf(rmax[i], e);
        }
    }
    float rsum[NN] = {0.f, 0.f, 0.f, 0.f, 0.f, 0.f};
    float nh[NN][4];
    #pragma unroll
    for (int i = 0; i < NN; ++i)
        #pragma unroll
        for (int c = 0; c < 4; ++c) nh[i][c] = 0.f;
    #pragma unroll
    for (int j = 0; j < NN; ++j) {
        float s[NN];
        #pragma unroll
        for (int i = 0; i < NN; ++i) {
            float e = ps[i] + pd[j];
            e = (e > 0.f) ? e : NEG * e;
            if ((mz >> (i * 6 + j)) & 1ull) e = MASKV;
            s[i] = expf(e - rmax[i]);
            rsum[i] += s[i];
        }
        #pragma unroll
        for (int i = 0; i < NN; ++i) {
            nh[i][0] = fmaf(s[i], wh[j][0], nh[i][0]);
            nh[i][1] = fmaf(s[i], wh[j][1], nh[i][1]);
            nh[i][2] = fmaf(s[i], wh[j][2], nh[i][2]);
            nh[i][3] = fmaf(s[i], wh[j][3], nh[i][3]);
        }
    }
    float* hout = hb + item * (NN * HIDD);
    #pragma unroll
    for (int i = 0; i < NN; ++i) {
        float rinv = 1.0f / rsum[i];
        if (LAST) {
            float4 v;
            v.x = fmaxf(nh[i][0] * rinv, 0.f);
            v.y = fmaxf(nh[i][1] * rinv, 0.f);
            v.z = fmaxf(nh[i][2] * rinv, 0.f);
            v.w = fmaxf(nh[i][3] * rinv, 0.f);
            *(float4*)(hout + i * HIDD + c0) = v;
        } else {
            #pragma unroll
            for (int c = 0; c < 4; ++c)
                hout[(c0 + c) * NN + i] = fmaxf(nh[i][c] * rinv, 0.f);
        }
    }
}

__global__ __launch_bounds__(NTHR) void nge_fused(
    const int* __restrict__ numbers,
    const float* __restrict__ adj,
    const float* __restrict__ emb,
    const float* __restrict__ W0, const float* __restrict__ a0,
    const float* __restrict__ W1, const float* __restrict__ a1,
    const float* __restrict__ W2, const float* __restrict__ a2,
    const float* __restrict__ P1w, const float* __restrict__ P1b,
    const float* __restrict__ P2w, const float* __restrict__ P2b,
    float* __restrict__ out)
{
    __shared__ float hbuf[TI * NN * HIDD];
    __shared__ float stage[12288];
    const int tid  = threadIdx.x;
    const int lane = tid & 63;
    const int item = tid >> 6;
    const int bidx = blockIdx.x * TI + item;
    {
        int rows[NN];
        #pragma unroll
        for (int i = 0; i < NN; ++i) rows[i] = numbers[bidx * NN + i];
        float* hitem = hbuf + item * (NN * HIDD);
        #pragma unroll
        for (int i = 0; i < NN; ++i) {
            #pragma unroll
            for (int r = 0; r < 2; ++r) {
                int f = lane + (r << 6);
                hitem[f * NN + i] = emb[rows[i] * EMBD + f];
            }
        }
    }
    unsigned long long mz;
    {
        float av = (lane < 36) ? adj[(size_t)bidx * 36 + lane] : 1.0f;
        mz = __ballot((lane < 36) && (av == 0.0f));
    }
    gat_layer<EMBD, false>(hbuf, stage, W0, a0, item, lane, tid, mz);
    gat_layer<HIDD, false>(hbuf, stage, W1, a1, item, lane, tid, mz);
    gat_layer<HIDD, true >(hbuf, stage, W2, a2, item, lane, tid, mz);
    const int ct  = tid & 127;
    const int rt  = tid >> 7;
    const int pc0 = ct << 2;
    float acc[2][4];
    #pragma unroll
    for (int t = 0; t < 2; ++t)
        #pragma unroll
        for (int c = 0; c < 4; ++c) acc[t][c] = 0.f;
    for (int g0 = 0; g0 < NN * HIDD; g0 += 24) {
        __syncthreads();
        #pragma unroll
        for (int s = 0; s < 3; ++s) {
            int r = rt + 8 * s;
            *(float4*)(stage + r * PROJD + pc0) =
                *(const float4*)(P1w + (size_t)(g0 + r) * PROJD + pc0);
        }
        __syncthreads();
        #pragma unroll
        for (int r4 = 0; r4 < 24; r4 += 4) {
            float4 A0 = *(const float4*)(hbuf + rt * (NN * HIDD) + g0 + r4);
            float4 A1 = *(const float4*)(hbuf + (rt + 8) * (NN * HIDD) + g0 + r4);
            const float a0v[4] = {A0.x, A0.y, A0.z, A0.w};
            const float a1v[4] = {A1.x, A1.y, A1.z, A1.w};
            #pragma unroll
            for (int rr = 0; rr < 4; ++rr) {
                float4 bv = *(const float4*)(stage + (r4 + rr) * PROJD + pc0);
                acc[0][0] = fmaf(a0v[rr], bv.x, acc[0][0]);
                acc[0][1] = fmaf(a0v[rr], bv.y, acc[0][1]);
                acc[0][2] = fmaf(a0v[rr], bv.z, acc[0][2]);
                acc[0][3] = fmaf(a0v[rr], bv.w, acc[0][3]);
                acc[1][0] = fmaf(a1v[rr], bv.x, acc[1][0]);
                acc[1][1] = fmaf(a1v[rr], bv.y, acc[1][1]);
                acc[1][2] = fmaf(a1v[rr], bv.z, acc[1][2]);
                acc[1][3] = fmaf(a1v[rr], bv.w, acc[1][3]);
            }
        }
    }
    __syncthreads();
    {
        float4 b1 = *(const float4*)(P1b + pc0);
        #pragma unroll
        for (int t = 0; t < 2; ++t) {
            int it = rt + 8 * t;
            float4 xv;
            xv.x = fmaxf(acc[t][0] + b1.x, 0.f);
            xv.y = fmaxf(acc[t][1] + b1.y, 0.f);
            xv.z = fmaxf(acc[t][2] + b1.z, 0.f);
            xv.w = fmaxf(acc[t][3] + b1.w, 0.f);
            *(float4*)(hbuf + it * PROJD + pc0) = xv;
        }
    }
    const int j0 = lane << 1;
    float acc2x = 0.f, acc2y = 0.f;
    for (int g0 = 0; g0 < PROJD; g0 += 64) {
        __syncthreads();
        {
            int r  = tid >> 5;
            int cc = (tid & 31) << 2;
            *(float4*)(stage + r * LAT2 + cc) =
                *(const float4*)(P2w + (size_t)(g0 + r) * LAT2 + cc);
            *(float4*)(stage + (r + 32) * LAT2 + cc) =
                *(const float4*)(P2w + (size_t)(g0 + r + 32) * LAT2 + cc);
        }
        __syncthreads();
        const float* xit = hbuf + item * PROJD + g0;
        #pragma unroll
        for (int r4 = 0; r4 < 64; r4 += 4) {
            float4 A = *(const float4*)(xit + r4);
            const float av[4] = {A.x, A.y, A.z, A.w};
            #pragma unroll
            for (int rr = 0; rr < 4; ++rr) {
                float2 bv = *(const float2*)(stage + (r4 + rr) * LAT2 + j0);
                acc2x = fmaf(av[rr], bv.x, acc2x);
                acc2y = fmaf(av[rr], bv.y, acc2y);
            }
        }
    }
    {
        float o0 = acc2x + P2b[j0];
        float o1 = acc2y + P2b[j0 + 1];
        size_t base = (size_t)bidx * 64;
        float2 v; v.x = o0; v.y = o1;
        if (j0 < 64) {
            *(float2*)(out + base + j0) = v;
        } else {
            *(float2*)(out + (size_t)BTOT * 64 + base + (j0 - 64)) = v;
        }
    }
}

// ======================= launch =========================================================
extern "C" void kernel_launch(void* const* d_in, const int* in_sizes, int n_in,
                              void* d_out, int out_size, void* d_ws, size_t ws_size,
                              hipStream_t stream) {
    const int*   numbers = (const int*)  d_in[0];
    const float* adj     = (const float*)d_in[1];
    const float* emb     = (const float*)d_in[2];
    const float* W0      = (const float*)d_in[3];
    const float* a0      = (const float*)d_in[4];
    const float* W1      = (const float*)d_in[5];
    const float* a1      = (const float*)d_in[6];
    const float* W2      = (const float*)d_in[7];
    const float* a2      = (const float*)d_in[8];
    const float* P1w     = (const float*)d_in[9];
    const float* P1b     = (const float*)d_in[10];
    const float* P2w     = (const float*)d_in[11];
    const float* P2b     = (const float*)d_in[12];
    float* out = (float*)d_out;

    if (ws_size >= WS_NEED) {
        char* ws = (char*)d_ws;
        fragize<<<1984, 64, 0, stream>>>(W0, W1, W2, P1w, P2w, ws);
        nge_mfma<<<BTOT/16, 1024, 0, stream>>>(numbers, adj, emb,
                                               a0, a1, a2, P1b, P2b, ws, out);
    } else {
        nge_fused<<<BTOT/TI, NTHR, 0, stream>>>(numbers, adj, emb,
                                                W0, a0, W1, a1, W2, a2,
                                                P1w, P1b, P2w, P2b, out);
    }
}